// Round 1
// baseline (132.355 us; speedup 1.0000x reference)
//
#include <hip/hip_runtime.h>
#include <hip/hip_bf16.h>

// Problem: B=2, L=S=2048, H=8, E=D=64. Dense attention (no mask/dropout).
// out[b,l,h,d] = softmax_s( (1/8) * sum_e Q[b,l,h,e]K[b,s,h,e] ) @ V[b,s,h,d]

#define LOG2E 1.44269504088896340736f

#if __has_builtin(__builtin_amdgcn_exp2f)
#define EXP2(x) __builtin_amdgcn_exp2f(x)
#else
#define EXP2(x) exp2f(x)
#endif

typedef __attribute__((ext_vector_type(8))) short bf16x8;   // 8 bf16 = 4 VGPRs
typedef __attribute__((ext_vector_type(4))) float f32x4;

static constexpr int Bc = 2, Lc = 2048, Sc = 2048, Hc = 8, Ec = 64, Dc = 64;
static constexpr int BH = Bc * Hc;                 // 16
static constexpr int ELEMS = Bc * Lc * Hc * Ec;    // 2097152 per tensor

static __device__ __forceinline__ unsigned short bfb(float x) {
  union { __hip_bfloat16 h; unsigned short u; } c;
  c.h = __float2bfloat16(x);
  return c.u;
}
static __device__ __forceinline__ unsigned pack2(float a, float b) {
  return (unsigned)bfb(a) | ((unsigned)bfb(b) << 16);
}

// ---- Pass 1: Q,K f32 [B,L,H,64] -> bf16 [B,H,L,64]; Q pre-scaled by 0.125 (exact) ----
__global__ __launch_bounds__(256) void cvt_qk_kernel(const float* __restrict__ Q,
                                                     const float* __restrict__ K,
                                                     __hip_bfloat16* __restrict__ Qc,
                                                     __hip_bfloat16* __restrict__ Kc) {
  const int N4 = ELEMS / 4;  // 524288 float4 groups per tensor
  int tid = blockIdx.x * 256 + threadIdx.x;   // grid sized exactly 2*N4
  bool isK = tid >= N4;
  int t = isK ? (tid - N4) : tid;
  const float* src = isK ? K : Q;
  __hip_bfloat16* dst = isK ? Kc : Qc;
  float scale = isK ? 1.0f : 0.125f;
  int f = t * 4;                 // flat = ((b*L + l)*H + h)*64 + e
  int e = f & 63;
  int h = (f >> 6) & 7;
  int bl = f >> 9;               // b*L + l
  int b = bl >> 11;
  int l = bl & 2047;
  float4 v = *reinterpret_cast<const float4*>(src + f);
  int o = (((b << 3) + h) * Lc + l) * 64 + e;  // [B,H,L,64]
  ushort4 w;
  w.x = bfb(v.x * scale);
  w.y = bfb(v.y * scale);
  w.z = bfb(v.z * scale);
  w.w = bfb(v.w * scale);
  *reinterpret_cast<ushort4*>(dst + o) = w;
}

// ---- Pass 2: V f32 [B,S,H,64] -> bf16 V^T [B,H,64,S] via LDS tile transpose ----
__global__ __launch_bounds__(64) void cvt_v_kernel(const float* __restrict__ V,
                                                   __hip_bfloat16* __restrict__ Vt) {
  __shared__ __hip_bfloat16 tile[64][65];  // pad to break bank alignment
  const int s0 = blockIdx.x * 64;
  const int bh = blockIdx.y;
  const int b = bh >> 3, h = bh & 7;
  const int lane = threadIdx.x;  // 64 threads = 1 wave
#pragma unroll 4
  for (int j = 0; j < 64; ++j) {
    float v = V[((b * Sc + s0 + j) * Hc + h) * 64 + lane];  // coalesced 256B
    tile[j][lane] = __float2bfloat16(v);
  }
  __syncthreads();
#pragma unroll 4
  for (int j = 0; j < 64; ++j) {
    // Vt[bh][d=j][s=s0+lane]
    Vt[(bh * 64 + j) * Sc + s0 + lane] = tile[lane][j];    // coalesced 128B
  }
}

// ---- Pass 3: flash attention, fully swapped MFMA layout ----
// Per wave: 16 q rows. Swapped QK^T: D = K_tile(16k x 32e) * Q^T(32e x 16q) -> S^T[key][q]:
//   lane holds q = lane&15, keys = kh*16 + (lane>>4)*4 + r  -> softmax row-local per lane.
// Swapped PV: D = V^T_tile(16d x 32k) * P^T(32k x 16q) -> O^T[d][q]: col q = lane&15, so
//   online rescale and final 1/l are pure per-lane ops.
__global__ __launch_bounds__(256) void attn_kernel(const __hip_bfloat16* __restrict__ Qc,
                                                   const __hip_bfloat16* __restrict__ Kc,
                                                   const __hip_bfloat16* __restrict__ Vt,
                                                   float* __restrict__ Out) {
  // P transpose scratch: per wave 16 rows x 80B (40 bf16, pad -> <=2-way conflicts, free)
  __shared__ __align__(16) unsigned char pbuf[4][16 * 80];

  const int bh = blockIdx.y;
  const int wave = threadIdx.x >> 6;
  const int lane = threadIdx.x & 63;
  const int qr = lane & 15;   // this lane's q row (swapped-layout column)
  const int g = lane >> 4;    // lane group 0..3
  const int q0 = blockIdx.x * 64 + wave * 16;

  const __hip_bfloat16* Qh = Qc + (bh * Lc + q0) * Ec;
  const __hip_bfloat16* Kh = Kc + bh * Sc * Ec;
  const __hip_bfloat16* Vh = Vt + bh * Dc * Sc;
  unsigned char* pl = pbuf[wave];

  // Q B-frag (Q^T operand): lane holds Q[q=qr][e = estep*32 + g*8 + i]
  bf16x8 qf0 = *reinterpret_cast<const bf16x8*>(Qh + qr * 64 + g * 8);
  bf16x8 qf1 = *reinterpret_cast<const bf16x8*>(Qh + qr * 64 + 32 + g * 8);

  f32x4 o0 = {0.f, 0.f, 0.f, 0.f}, o1 = o0, o2 = o0, o3 = o0;
  float m = -3.0e38f, lsum = 0.f;

  for (int s0 = 0; s0 < Sc; s0 += 32) {
    // K A-frag: lane holds K[key = kh*16 + (lane&15)][e = estep*32 + g*8 + i]
    const __hip_bfloat16* Kp = Kh + (s0 + qr) * 64 + g * 8;
    bf16x8 k00 = *reinterpret_cast<const bf16x8*>(Kp);
    bf16x8 k01 = *reinterpret_cast<const bf16x8*>(Kp + 32);
    bf16x8 k10 = *reinterpret_cast<const bf16x8*>(Kp + 16 * 64);
    bf16x8 k11 = *reinterpret_cast<const bf16x8*>(Kp + 16 * 64 + 32);

    f32x4 sa = {0.f, 0.f, 0.f, 0.f};
    f32x4 sb = {0.f, 0.f, 0.f, 0.f};
    sa = __builtin_amdgcn_mfma_f32_16x16x32_bf16(k00, qf0, sa, 0, 0, 0);
    sa = __builtin_amdgcn_mfma_f32_16x16x32_bf16(k01, qf1, sa, 0, 0, 0);
    sb = __builtin_amdgcn_mfma_f32_16x16x32_bf16(k10, qf0, sb, 0, 0, 0);
    sb = __builtin_amdgcn_mfma_f32_16x16x32_bf16(k11, qf1, sb, 0, 0, 0);
    // lane now holds S^T for q=qr: sa[r] -> key g*4+r, sb[r] -> key 16+g*4+r

    // online softmax (scores already scaled by 0.125 via Q prescale)
    float mx = fmaxf(fmaxf(fmaxf(sa[0], sa[1]), fmaxf(sa[2], sa[3])),
                     fmaxf(fmaxf(sb[0], sb[1]), fmaxf(sb[2], sb[3])));
    mx = fmaxf(mx, __shfl_xor(mx, 16));
    mx = fmaxf(mx, __shfl_xor(mx, 32));
    float mnew = fmaxf(m, mx);
    float corr = EXP2((m - mnew) * LOG2E);
    float p0 = EXP2((sa[0] - mnew) * LOG2E);
    float p1 = EXP2((sa[1] - mnew) * LOG2E);
    float p2 = EXP2((sa[2] - mnew) * LOG2E);
    float p3 = EXP2((sa[3] - mnew) * LOG2E);
    float p4 = EXP2((sb[0] - mnew) * LOG2E);
    float p5 = EXP2((sb[1] - mnew) * LOG2E);
    float p6 = EXP2((sb[2] - mnew) * LOG2E);
    float p7 = EXP2((sb[3] - mnew) * LOG2E);
    float rs = ((p0 + p1) + (p2 + p3)) + ((p4 + p5) + (p6 + p7));
    rs += __shfl_xor(rs, 16);
    rs += __shfl_xor(rs, 32);
    lsum = lsum * corr + rs;
    m = mnew;
    o0 *= corr; o1 *= corr; o2 *= corr; o3 *= corr;

    // P^T -> LDS in [q][key] order (bf16), then re-read as B-frag (8 consecutive keys)
    uint2 wlo, whi;
    wlo.x = pack2(p0, p1);
    wlo.y = pack2(p2, p3);
    whi.x = pack2(p4, p5);
    whi.y = pack2(p6, p7);
    *reinterpret_cast<uint2*>(pl + qr * 80 + 8 * g) = wlo;        // keys 4g..4g+3
    *reinterpret_cast<uint2*>(pl + qr * 80 + 32 + 8 * g) = whi;   // keys 16+4g..16+4g+3
    // wave-synchronous cross-lane LDS reuse: force the drain (compiler AA must not skip it)
    asm volatile("s_waitcnt lgkmcnt(0)" ::: "memory");
    __builtin_amdgcn_sched_barrier(0);
    bf16x8 pf = *reinterpret_cast<const bf16x8*>(pl + qr * 80 + 16 * g);  // P[q=qr][8g..8g+7]

    // PV (swapped): A = V^T tile: lane holds Vt[d = dt*16 + qr][key = s0 + g*8 + i]
    const __hip_bfloat16* Vp = Vh + qr * Sc + s0 + g * 8;
    bf16x8 v0 = *reinterpret_cast<const bf16x8*>(Vp);
    bf16x8 v1 = *reinterpret_cast<const bf16x8*>(Vp + 16 * Sc);
    bf16x8 v2 = *reinterpret_cast<const bf16x8*>(Vp + 32 * Sc);
    bf16x8 v3 = *reinterpret_cast<const bf16x8*>(Vp + 48 * Sc);
    o0 = __builtin_amdgcn_mfma_f32_16x16x32_bf16(v0, pf, o0, 0, 0, 0);
    o1 = __builtin_amdgcn_mfma_f32_16x16x32_bf16(v1, pf, o1, 0, 0, 0);
    o2 = __builtin_amdgcn_mfma_f32_16x16x32_bf16(v2, pf, o2, 0, 0, 0);
    o3 = __builtin_amdgcn_mfma_f32_16x16x32_bf16(v3, pf, o3, 0, 0, 0);
  }

  // epilogue: o[dt][r] = O^T[d = dt*16 + g*4 + r][q = qr]; out[b, q0+qr, h, d] (f32)
  float inv = 1.0f / lsum;
  const int b = bh >> 3, h = bh & 7;
  float* orow = Out + ((b * Lc + q0 + qr) * Hc + h) * Dc;
  o0 *= inv; o1 *= inv; o2 *= inv; o3 *= inv;
  *reinterpret_cast<f32x4*>(orow + 0 * 16 + g * 4) = o0;
  *reinterpret_cast<f32x4*>(orow + 1 * 16 + g * 4) = o1;
  *reinterpret_cast<f32x4*>(orow + 2 * 16 + g * 4) = o2;
  *reinterpret_cast<f32x4*>(orow + 3 * 16 + g * 4) = o3;
}

extern "C" void kernel_launch(void* const* d_in, const int* in_sizes, int n_in,
                              void* d_out, int out_size, void* d_ws, size_t ws_size,
                              hipStream_t stream) {
  const float* Q = (const float*)d_in[0];
  const float* K = (const float*)d_in[1];
  const float* V = (const float*)d_in[2];
  float* out = (float*)d_out;

  // workspace layout: Qc | Kc | Vt, each ELEMS bf16 (4 MiB) -> 12 MiB total
  __hip_bfloat16* Qc = (__hip_bfloat16*)d_ws;
  __hip_bfloat16* Kc = Qc + ELEMS;
  __hip_bfloat16* Vt = Kc + ELEMS;

  // pass 1: Q+K convert/relayout. 2*ELEMS/4 threads exactly.
  cvt_qk_kernel<<<(2 * ELEMS / 4) / 256, 256, 0, stream>>>(Q, K, Qc, Kc);
  // pass 2: V transpose to [B,H,64,S]
  cvt_v_kernel<<<dim3(Sc / 64, BH), 64, 0, stream>>>(V, Vt);
  // pass 3: attention. 32 q-tiles x 16 heads, 4 waves/block (16 q rows each).
  attn_kernel<<<dim3(Lc / 64, BH), 256, 0, stream>>>(Qc, Kc, Vt, out);
}

// Round 2
// 80.941 us; speedup vs baseline: 1.6352x; 1.6352x over previous
//
#include <hip/hip_runtime.h>
#include <hip/hip_bf16.h>

// B=2, L=S=2048, H=8, E=D=64. Dense attention.
// out[b,l,h,d] = softmax_s( (1/8) * sum_e Q[b,l,h,e]K[b,s,h,e] ) @ V[b,s,h,d]

#define LOG2E 1.44269504088896340736f

#if __has_builtin(__builtin_amdgcn_exp2f)
#define EXP2(x) __builtin_amdgcn_exp2f(x)
#else
#define EXP2(x) exp2f(x)
#endif

typedef __attribute__((ext_vector_type(8))) short bf16x8;   // 8 bf16 = 4 VGPRs
typedef __attribute__((ext_vector_type(4))) float f32x4;

static constexpr int Bc = 2, Lc = 2048, Sc = 2048, Hc = 8, Ec = 64, Dc = 64;
static constexpr int BH = Bc * Hc;                 // 16
static constexpr int ELEMS = Bc * Lc * Hc * Ec;    // 2097152 per tensor

static __device__ __forceinline__ unsigned short bfb(float x) {
  union { __hip_bfloat16 h; unsigned short u; } c;
  c.h = __float2bfloat16(x);
  return c.u;
}
static __device__ __forceinline__ unsigned pack2(float a, float b) {
  return (unsigned)bfb(a) | ((unsigned)bfb(b) << 16);
}

// ---- Pass 1: Q,K f32 [B,L,H,64] -> bf16 [B,H,L,64]; Q pre-scaled by 0.125 (exact) ----
__global__ __launch_bounds__(256) void cvt_qk_kernel(const float* __restrict__ Q,
                                                     const float* __restrict__ K,
                                                     __hip_bfloat16* __restrict__ Qc,
                                                     __hip_bfloat16* __restrict__ Kc) {
  const int N4 = ELEMS / 4;
  int tid = blockIdx.x * 256 + threadIdx.x;
  bool isK = tid >= N4;
  int t = isK ? (tid - N4) : tid;
  const float* src = isK ? K : Q;
  __hip_bfloat16* dst = isK ? Kc : Qc;
  float scale = isK ? 1.0f : 0.125f;
  int f = t * 4;                 // flat = ((b*L + l)*H + h)*64 + e
  int e = f & 63;
  int h = (f >> 6) & 7;
  int bl = f >> 9;
  int b = bl >> 11;
  int l = bl & 2047;
  float4 v = *reinterpret_cast<const float4*>(src + f);
  int o = (((b << 3) + h) * Lc + l) * 64 + e;  // [B,H,L,64]
  ushort4 w;
  w.x = bfb(v.x * scale);
  w.y = bfb(v.y * scale);
  w.z = bfb(v.z * scale);
  w.w = bfb(v.w * scale);
  *reinterpret_cast<ushort4*>(dst + o) = w;
}

// ---- Pass 2: V f32 [B,S,H,64] -> bf16 V^T [B,H,64,S] via LDS tile transpose ----
__global__ __launch_bounds__(64) void cvt_v_kernel(const float* __restrict__ V,
                                                   __hip_bfloat16* __restrict__ Vt) {
  __shared__ __hip_bfloat16 tile[64][65];
  const int s0 = blockIdx.x * 64;
  const int bh = blockIdx.y;
  const int b = bh >> 3, h = bh & 7;
  const int lane = threadIdx.x;
#pragma unroll 4
  for (int j = 0; j < 64; ++j) {
    float v = V[((b * Sc + s0 + j) * Hc + h) * 64 + lane];
    tile[j][lane] = __float2bfloat16(v);
  }
  __syncthreads();
#pragma unroll 4
  for (int j = 0; j < 64; ++j) {
    Vt[(bh * 64 + j) * Sc + s0 + lane] = tile[lane][j];
  }
}

// online-softmax step for one 16-q-row half; sa = keys g*4+r, sb = keys 16+g*4+r
static __device__ __forceinline__ void softmax_step(const f32x4& sa, const f32x4& sb,
                                                    float& m, float& l, float& corr,
                                                    uint2& wlo, uint2& whi) {
  float mx = fmaxf(fmaxf(fmaxf(sa[0], sa[1]), fmaxf(sa[2], sa[3])),
                   fmaxf(fmaxf(sb[0], sb[1]), fmaxf(sb[2], sb[3])));
  mx = fmaxf(mx, __shfl_xor(mx, 16));
  mx = fmaxf(mx, __shfl_xor(mx, 32));
  float mnew = fmaxf(m, mx);
  corr = EXP2((m - mnew) * LOG2E);
  float p0 = EXP2((sa[0] - mnew) * LOG2E);
  float p1 = EXP2((sa[1] - mnew) * LOG2E);
  float p2 = EXP2((sa[2] - mnew) * LOG2E);
  float p3 = EXP2((sa[3] - mnew) * LOG2E);
  float p4 = EXP2((sb[0] - mnew) * LOG2E);
  float p5 = EXP2((sb[1] - mnew) * LOG2E);
  float p6 = EXP2((sb[2] - mnew) * LOG2E);
  float p7 = EXP2((sb[3] - mnew) * LOG2E);
  float rs = ((p0 + p1) + (p2 + p3)) + ((p4 + p5) + (p6 + p7));
  rs += __shfl_xor(rs, 16);
  rs += __shfl_xor(rs, 32);
  l = l * corr + rs;
  m = mnew;
  wlo.x = pack2(p0, p1);
  wlo.y = pack2(p2, p3);
  whi.x = pack2(p4, p5);
  whi.y = pack2(p6, p7);
}

// ---- Pass 3: flash attention, swapped MFMA layout, 32 q-rows/wave, S-split x4 ----
// Grid: 1024 blocks (1-D), XCD-swizzled so each XCD owns 2 (b,h) heads (K/V 1MB -> L2-resident).
// Block: 4 waves; all share one 32-q-row tile; wave w handles keys [w*512, w*512+512).
// Swapped QK^T: S^T[key][q] per lane (q = lane&15 within each 16-row half) -> row softmax is
// per-lane + 2 shfl. Swapped PV: O^T[d][q] -> rescale is per-lane. Waves combine m/l/O via LDS.
__global__ __launch_bounds__(256) void attn_kernel(const __hip_bfloat16* __restrict__ Qc,
                                                   const __hip_bfloat16* __restrict__ Kc,
                                                   const __hip_bfloat16* __restrict__ Vt,
                                                   float* __restrict__ Out) {
  __shared__ __align__(16) unsigned char pbuf[4][32 * 80];   // P^T transpose, per-wave
  __shared__ __align__(16) float obuf[4][4][64][4];          // [srcwave][dt][lane][r] 16KB
  __shared__ float mlb[2][4][2][16];                         // [qh][wave][{m,l}][qr]

  const int lid = blockIdx.x;         // 1024 = 8 xcd * 2 heads * 64 qtiles
  const int xcd = lid & 7;
  const int i = lid >> 3;             // 0..127
  const int bh = (xcd << 1) | (i >> 6);
  const int q0 = (i & 63) << 5;       // 32 q rows per block
  const int w = threadIdx.x >> 6;
  const int lane = threadIdx.x & 63;
  const int qr = lane & 15;
  const int g = lane >> 4;

  const __hip_bfloat16* Qh = Qc + (bh * Lc + q0) * Ec;
  const __hip_bfloat16* Kh = Kc + bh * Sc * Ec;
  const __hip_bfloat16* Vh = Vt + bh * Dc * Sc;
  unsigned char* pl = pbuf[w];

  // Q B-frags: qf[qh][es] -> Q[q = qh*16+qr][e = es*32 + g*8 + i]
  bf16x8 qf[2][2];
#pragma unroll
  for (int qh = 0; qh < 2; ++qh)
#pragma unroll
    for (int es = 0; es < 2; ++es)
      qf[qh][es] = *reinterpret_cast<const bf16x8*>(Qh + (qh * 16 + qr) * 64 + es * 32 + g * 8);

  f32x4 o[4][2];
#pragma unroll
  for (int dt = 0; dt < 4; ++dt)
#pragma unroll
    for (int qh = 0; qh < 2; ++qh)
      o[dt][qh] = (f32x4){0.f, 0.f, 0.f, 0.f};
  float m0 = -3.0e38f, m1 = -3.0e38f, l0 = 0.f, l1 = 0.f;

  const int sBeg = w * 512, sEnd = sBeg + 512;
  for (int s = sBeg; s < sEnd; s += 32) {
    // K A-frags: keys s+qr and s+16+qr
    const __hip_bfloat16* Kp = Kh + (s + qr) * 64 + g * 8;
    bf16x8 k00 = *reinterpret_cast<const bf16x8*>(Kp);
    bf16x8 k01 = *reinterpret_cast<const bf16x8*>(Kp + 32);
    bf16x8 k10 = *reinterpret_cast<const bf16x8*>(Kp + 16 * 64);
    bf16x8 k11 = *reinterpret_cast<const bf16x8*>(Kp + 16 * 64 + 32);
    // V A-frags for this iter, issued early: latency hides under softmax
    const __hip_bfloat16* Vp = Vh + qr * Sc + s + g * 8;
    bf16x8 v0 = *reinterpret_cast<const bf16x8*>(Vp);
    bf16x8 v1 = *reinterpret_cast<const bf16x8*>(Vp + 16 * Sc);
    bf16x8 v2 = *reinterpret_cast<const bf16x8*>(Vp + 32 * Sc);
    bf16x8 v3 = *reinterpret_cast<const bf16x8*>(Vp + 48 * Sc);

    f32x4 s00 = {0.f, 0.f, 0.f, 0.f}, s01 = s00, s10 = s00, s11 = s00;  // [kb][qh]
    s00 = __builtin_amdgcn_mfma_f32_16x16x32_bf16(k00, qf[0][0], s00, 0, 0, 0);
    s00 = __builtin_amdgcn_mfma_f32_16x16x32_bf16(k01, qf[0][1], s00, 0, 0, 0);
    s01 = __builtin_amdgcn_mfma_f32_16x16x32_bf16(k00, qf[1][0], s01, 0, 0, 0);
    s01 = __builtin_amdgcn_mfma_f32_16x16x32_bf16(k01, qf[1][1], s01, 0, 0, 0);
    s10 = __builtin_amdgcn_mfma_f32_16x16x32_bf16(k10, qf[0][0], s10, 0, 0, 0);
    s10 = __builtin_amdgcn_mfma_f32_16x16x32_bf16(k11, qf[0][1], s10, 0, 0, 0);
    s11 = __builtin_amdgcn_mfma_f32_16x16x32_bf16(k10, qf[1][0], s11, 0, 0, 0);
    s11 = __builtin_amdgcn_mfma_f32_16x16x32_bf16(k11, qf[1][1], s11, 0, 0, 0);

    float c0, c1;
    uint2 wlo0, whi0, wlo1, whi1;
    softmax_step(s00, s10, m0, l0, c0, wlo0, whi0);
    softmax_step(s01, s11, m1, l1, c1, wlo1, whi1);
#pragma unroll
    for (int dt = 0; dt < 4; ++dt) { o[dt][0] *= c0; o[dt][1] *= c1; }

    // P^T -> LDS (rows qr and 16+qr), re-read as B-frags
    *reinterpret_cast<uint2*>(pl + qr * 80 + 8 * g) = wlo0;
    *reinterpret_cast<uint2*>(pl + qr * 80 + 32 + 8 * g) = whi0;
    *reinterpret_cast<uint2*>(pl + (16 + qr) * 80 + 8 * g) = wlo1;
    *reinterpret_cast<uint2*>(pl + (16 + qr) * 80 + 32 + 8 * g) = whi1;
    asm volatile("s_waitcnt lgkmcnt(0)" ::: "memory");
    __builtin_amdgcn_sched_barrier(0x20);  // only VMEM reads may cross (prefetch next iter)
    bf16x8 pf0 = *reinterpret_cast<const bf16x8*>(pl + qr * 80 + 16 * g);
    bf16x8 pf1 = *reinterpret_cast<const bf16x8*>(pl + (16 + qr) * 80 + 16 * g);

    o[0][0] = __builtin_amdgcn_mfma_f32_16x16x32_bf16(v0, pf0, o[0][0], 0, 0, 0);
    o[1][0] = __builtin_amdgcn_mfma_f32_16x16x32_bf16(v1, pf0, o[1][0], 0, 0, 0);
    o[2][0] = __builtin_amdgcn_mfma_f32_16x16x32_bf16(v2, pf0, o[2][0], 0, 0, 0);
    o[3][0] = __builtin_amdgcn_mfma_f32_16x16x32_bf16(v3, pf0, o[3][0], 0, 0, 0);
    o[0][1] = __builtin_amdgcn_mfma_f32_16x16x32_bf16(v0, pf1, o[0][1], 0, 0, 0);
    o[1][1] = __builtin_amdgcn_mfma_f32_16x16x32_bf16(v1, pf1, o[1][1], 0, 0, 0);
    o[2][1] = __builtin_amdgcn_mfma_f32_16x16x32_bf16(v2, pf1, o[2][1], 0, 0, 0);
    o[3][1] = __builtin_amdgcn_mfma_f32_16x16x32_bf16(v3, pf1, o[3][1], 0, 0, 0);
  }

  // ---- cross-wave combine (4 S-split partials) ----
  if (g == 0) {
    mlb[0][w][0][qr] = m0; mlb[0][w][1][qr] = l0;
    mlb[1][w][0][qr] = m1; mlb[1][w][1][qr] = l1;
  }
  __syncthreads();
  float myf[2], inv[2];
#pragma unroll
  for (int qh = 0; qh < 2; ++qh) {
    float mm = mlb[qh][0][0][qr];
#pragma unroll
    for (int sw = 1; sw < 4; ++sw) mm = fmaxf(mm, mlb[qh][sw][0][qr]);
    float Lt = 0.f;
#pragma unroll
    for (int sw = 0; sw < 4; ++sw)
      Lt += EXP2((mlb[qh][sw][0][qr] - mm) * LOG2E) * mlb[qh][sw][1][qr];
    float mreg = qh ? m1 : m0;
    myf[qh] = EXP2((mreg - mm) * LOG2E);
    inv[qh] = 1.0f / Lt;
  }
  const int b = bh >> 3, h = bh & 7;
#pragma unroll
  for (int qh = 0; qh < 2; ++qh) {
#pragma unroll
    for (int dt = 0; dt < 4; ++dt) {
      f32x4 t = o[dt][qh] * myf[qh];
      *reinterpret_cast<f32x4*>(&obuf[w][dt][lane][0]) = t;
    }
    __syncthreads();
    f32x4 acc = {0.f, 0.f, 0.f, 0.f};
#pragma unroll
    for (int sw = 0; sw < 4; ++sw)
      acc += *reinterpret_cast<const f32x4*>(&obuf[sw][w][lane][0]);
    acc *= inv[qh];
    float* orow = Out + ((b * Lc + q0 + qh * 16 + qr) * Hc + h) * Dc + w * 16 + g * 4;
    *reinterpret_cast<f32x4*>(orow) = acc;
    __syncthreads();
  }
}

extern "C" void kernel_launch(void* const* d_in, const int* in_sizes, int n_in,
                              void* d_out, int out_size, void* d_ws, size_t ws_size,
                              hipStream_t stream) {
  const float* Q = (const float*)d_in[0];
  const float* K = (const float*)d_in[1];
  const float* V = (const float*)d_in[2];
  float* out = (float*)d_out;

  __hip_bfloat16* Qc = (__hip_bfloat16*)d_ws;
  __hip_bfloat16* Kc = Qc + ELEMS;
  __hip_bfloat16* Vt = Kc + ELEMS;

  cvt_qk_kernel<<<(2 * ELEMS / 4) / 256, 256, 0, stream>>>(Q, K, Qc, Kc);
  cvt_v_kernel<<<dim3(Sc / 64, BH), 64, 0, stream>>>(V, Vt);
  // 1024 blocks: 8 XCDs x 2 heads x 64 q-tiles (swizzle-decoded in-kernel)
  attn_kernel<<<dim3(1024), 256, 0, stream>>>(Qc, Kc, Vt, out);
}

// Round 3
// 79.849 us; speedup vs baseline: 1.6576x; 1.0137x over previous
//
#include <hip/hip_runtime.h>
#include <hip/hip_bf16.h>

// B=2, L=S=2048, H=8, E=D=64. Dense attention.
// out[b,l,h,d] = softmax_s( (1/8) * sum_e Q[b,l,h,e]K[b,s,h,e] ) @ V[b,s,h,d]

#define LOG2E 1.44269504088896340736f

#if __has_builtin(__builtin_amdgcn_exp2f)
#define EXP2(x) __builtin_amdgcn_exp2f(x)
#else
#define EXP2(x) exp2f(x)
#endif

typedef __attribute__((ext_vector_type(8))) short bf16x8;   // 8 bf16 = 4 VGPRs
typedef __attribute__((ext_vector_type(4))) float f32x4;
typedef __attribute__((ext_vector_type(16))) float f32x16;

static constexpr int Bc = 2, Lc = 2048, Sc = 2048, Hc = 8, Ec = 64, Dc = 64;
static constexpr int BH = Bc * Hc;                 // 16
static constexpr int ELEMS = Bc * Lc * Hc * Ec;    // 2097152 per tensor

static __device__ __forceinline__ unsigned short bfb(float x) {
  union { __hip_bfloat16 h; unsigned short u; } c;
  c.h = __float2bfloat16(x);
  return c.u;
}

// ---- Pass 1: Q,K f32 [B,L,H,64] -> bf16 [B,H,L,64]; Q pre-scaled by 0.125 (exact) ----
__global__ __launch_bounds__(256) void cvt_qk_kernel(const float* __restrict__ Q,
                                                     const float* __restrict__ K,
                                                     __hip_bfloat16* __restrict__ Qc,
                                                     __hip_bfloat16* __restrict__ Kc) {
  const int N4 = ELEMS / 4;
  int tid = blockIdx.x * 256 + threadIdx.x;
  bool isK = tid >= N4;
  int t = isK ? (tid - N4) : tid;
  const float* src = isK ? K : Q;
  __hip_bfloat16* dst = isK ? Kc : Qc;
  float scale = isK ? 1.0f : 0.125f;
  int f = t * 4;                 // flat = ((b*L + l)*H + h)*64 + e
  int e = f & 63;
  int h = (f >> 6) & 7;
  int bl = f >> 9;
  int b = bl >> 11;
  int l = bl & 2047;
  float4 v = *reinterpret_cast<const float4*>(src + f);
  int o = (((b << 3) + h) * Lc + l) * 64 + e;  // [B,H,L,64]
  ushort4 w;
  w.x = bfb(v.x * scale);
  w.y = bfb(v.y * scale);
  w.z = bfb(v.z * scale);
  w.w = bfb(v.w * scale);
  *reinterpret_cast<ushort4*>(dst + o) = w;
}

// ---- Pass 2: V f32 [B,S,H,64] -> bf16 V^T [B,H,64,S] via LDS tile transpose ----
__global__ __launch_bounds__(64) void cvt_v_kernel(const float* __restrict__ V,
                                                   __hip_bfloat16* __restrict__ Vt) {
  __shared__ __hip_bfloat16 tile[64][65];
  const int s0 = blockIdx.x * 64;
  const int bh = blockIdx.y;
  const int b = bh >> 3, h = bh & 7;
  const int lane = threadIdx.x;
#pragma unroll 4
  for (int j = 0; j < 64; ++j) {
    float v = V[((b * Sc + s0 + j) * Hc + h) * 64 + lane];
    tile[j][lane] = __float2bfloat16(v);
  }
  __syncthreads();
#pragma unroll 4
  for (int j = 0; j < 64; ++j) {
    Vt[(bh * 64 + j) * Sc + s0 + lane] = tile[lane][j];
  }
}

// permlane32_swap: after op, o0 = [a.lo | b.lo], o1 = [a.hi | b.hi] (half-row exchange)
static __device__ __forceinline__ void plswap(unsigned a, unsigned b,
                                              unsigned& o0, unsigned& o1, int hi) {
#if __has_builtin(__builtin_amdgcn_permlane32_swap)
  auto r = __builtin_amdgcn_permlane32_swap(a, b, false, false);
  o0 = r[0];
  o1 = r[1];
#else
  unsigned ax = (unsigned)__shfl_xor((int)a, 32);
  unsigned bx = (unsigned)__shfl_xor((int)b, 32);
  o0 = hi ? bx : a;
  o1 = hi ? b : ax;
#endif
}

static __device__ __forceinline__ unsigned pkbf(float a, float b) {
  union { __hip_bfloat162 h; unsigned u; } c;
  c.h = __float22bfloat162_rn(make_float2(a, b));  // -> v_cvt_pk_bf16_f32
  return c.u;
}

static __device__ __forceinline__ bf16x8 pack4(unsigned w0, unsigned w1,
                                               unsigned w2, unsigned w3) {
  union { unsigned u[4]; bf16x8 v; } c;
  c.u[0] = w0; c.u[1] = w1; c.u[2] = w2; c.u[3] = w3;
  return c.v;
}

// ---- Pass 3: flash attention, 32x32 swapped MFMA layout (m214 structure) ----
// Grid: 1024 blocks, XCD-pinned: each XCD owns 2 (b,h) heads (K/V 1MB -> L2-resident).
// Block: 4 waves share one 32-q-row tile; wave w handles keys s = w*32 + 128*t (interleaved).
// QK^T swapped: S^T = K(32k x 16e) x Q^T -> lane q = lane&31 holds 16 of 32 key-scores:
//   key(r,hi) = (r&3) + 8*(r>>2) + 4*hi. Softmax = in-lane tree + 1 permlane32_swap.
// P -> bf16 B-frags via cvt_pk + 4 permlane32_swap (no LDS, no shuffles in loop).
// PV swapped: O^T = V^T(32d x 16k) x P^T -> per-lane rescale. LDS only for final combine.
__global__ __launch_bounds__(256, 4) void attn_kernel(const __hip_bfloat16* __restrict__ Qc,
                                                      const __hip_bfloat16* __restrict__ Kc,
                                                      const __hip_bfloat16* __restrict__ Vt,
                                                      float* __restrict__ Out) {
  __shared__ float obuf[4][2][16][64];  // [wave][d0][reg][lane] 32KB, conflict-free
  __shared__ float mlb[4][2][32];       // [wave][{m,l}][q]

  const int lid = blockIdx.x;           // 1024 = 8 xcd * 2 heads * 64 qtiles
  const int xcd = lid & 7;
  const int i = lid >> 3;
  const int bh = (xcd << 1) | (i >> 6);
  const int q0 = (i & 63) << 5;         // 32 q rows per block
  const int w = threadIdx.x >> 6;
  const int lane = threadIdx.x & 63;
  const int qi = lane & 31;             // this lane's q row
  const int hi = lane >> 5;

  const __hip_bfloat16* Qh = Qc + (bh * Lc + q0) * Ec;
  const __hip_bfloat16* Kh = Kc + bh * Sc * Ec;
  const __hip_bfloat16* Vh = Vt + bh * Dc * Sc;

  // Q B-frags: qf[es] -> Q[q=qi][e = es*16 + hi*8 + j]
  bf16x8 qf0 = *reinterpret_cast<const bf16x8*>(Qh + qi * 64 + 0 * 16 + hi * 8);
  bf16x8 qf1 = *reinterpret_cast<const bf16x8*>(Qh + qi * 64 + 1 * 16 + hi * 8);
  bf16x8 qf2 = *reinterpret_cast<const bf16x8*>(Qh + qi * 64 + 2 * 16 + hi * 8);
  bf16x8 qf3 = *reinterpret_cast<const bf16x8*>(Qh + qi * 64 + 3 * 16 + hi * 8);

  f32x16 oa, ob;                         // O^T accum: d = d0*32 + key-pattern
#pragma unroll
  for (int r = 0; r < 16; ++r) { oa[r] = 0.f; ob[r] = 0.f; }
  float m = -1.0e30f, l = 0.f;

  for (int s = w * 32; s < Sc; s += 128) {
    // K A-frags: K[key = s+qi][e = es*16 + hi*8 + j]
    const __hip_bfloat16* Kp = Kh + (s + qi) * 64 + hi * 8;
    bf16x8 k0 = *reinterpret_cast<const bf16x8*>(Kp);
    bf16x8 k1 = *reinterpret_cast<const bf16x8*>(Kp + 16);
    bf16x8 k2 = *reinterpret_cast<const bf16x8*>(Kp + 32);
    bf16x8 k3 = *reinterpret_cast<const bf16x8*>(Kp + 48);
    // V A-frags: Vt[d = d0*32+qi][k = s + ks*16 + hi*8 + j] (early issue: hide under QK)
    const __hip_bfloat16* Vp = Vh + qi * Sc + s + hi * 8;
    bf16x8 v00 = *reinterpret_cast<const bf16x8*>(Vp);
    bf16x8 v01 = *reinterpret_cast<const bf16x8*>(Vp + 16);
    bf16x8 v10 = *reinterpret_cast<const bf16x8*>(Vp + 32 * Sc);
    bf16x8 v11 = *reinterpret_cast<const bf16x8*>(Vp + 32 * Sc + 16);

    f32x16 sc;
#pragma unroll
    for (int r = 0; r < 16; ++r) sc[r] = 0.f;
    sc = __builtin_amdgcn_mfma_f32_32x32x16_bf16(k0, qf0, sc, 0, 0, 0);
    sc = __builtin_amdgcn_mfma_f32_32x32x16_bf16(k1, qf1, sc, 0, 0, 0);
    sc = __builtin_amdgcn_mfma_f32_32x32x16_bf16(k2, qf2, sc, 0, 0, 0);
    sc = __builtin_amdgcn_mfma_f32_32x32x16_bf16(k3, qf3, sc, 0, 0, 0);

    // row max: 15 in-lane fmax + 1 permlane cross-half
    float x0 = fmaxf(fmaxf(sc[0], sc[1]), fmaxf(sc[2], sc[3]));
    float x1 = fmaxf(fmaxf(sc[4], sc[5]), fmaxf(sc[6], sc[7]));
    float x2 = fmaxf(fmaxf(sc[8], sc[9]), fmaxf(sc[10], sc[11]));
    float x3 = fmaxf(fmaxf(sc[12], sc[13]), fmaxf(sc[14], sc[15]));
    float mx = fmaxf(fmaxf(x0, x1), fmaxf(x2, x3));
    unsigned ua, ub;
    plswap(__float_as_uint(mx), __float_as_uint(mx), ua, ub, hi);
    mx = fmaxf(__uint_as_float(ua), __uint_as_float(ub));

    // defer-max (T13): only rescale when the running max grew by > 8 (P bounded by e^8)
    if (__any(mx > m + 8.0f)) {
      float mnew = fmaxf(m, mx);
      float corr = EXP2((m - mnew) * LOG2E);
      l *= corr;
#pragma unroll
      for (int r = 0; r < 16; ++r) { oa[r] *= corr; ob[r] *= corr; }
      m = mnew;
    }

#pragma unroll
    for (int r = 0; r < 16; ++r) sc[r] = EXP2((sc[r] - m) * LOG2E);

    float r0 = (sc[0] + sc[1]) + (sc[2] + sc[3]);
    float r1 = (sc[4] + sc[5]) + (sc[6] + sc[7]);
    float r2 = (sc[8] + sc[9]) + (sc[10] + sc[11]);
    float r3 = (sc[12] + sc[13]) + (sc[14] + sc[15]);
    float rs = (r0 + r1) + (r2 + r3);
    plswap(__float_as_uint(rs), __float_as_uint(rs), ua, ub, hi);
    rs = __uint_as_float(ua) + __uint_as_float(ub);
    l += rs;

    // P^T B-frags via cvt_pk + permlane32_swap (T12). Slice ks: keys 16ks + 8hi + j.
    unsigned c0, c1, c2, c3, w0, w1, w2, w3;
    c0 = pkbf(sc[0], sc[1]);  c1 = pkbf(sc[4], sc[5]);
    c2 = pkbf(sc[2], sc[3]);  c3 = pkbf(sc[6], sc[7]);
    plswap(c0, c1, w0, w2, hi);
    plswap(c2, c3, w1, w3, hi);
    bf16x8 pb0 = pack4(w0, w1, w2, w3);
    c0 = pkbf(sc[8], sc[9]);   c1 = pkbf(sc[12], sc[13]);
    c2 = pkbf(sc[10], sc[11]); c3 = pkbf(sc[14], sc[15]);
    plswap(c0, c1, w0, w2, hi);
    plswap(c2, c3, w1, w3, hi);
    bf16x8 pb1 = pack4(w0, w1, w2, w3);

    oa = __builtin_amdgcn_mfma_f32_32x32x16_bf16(v00, pb0, oa, 0, 0, 0);
    oa = __builtin_amdgcn_mfma_f32_32x32x16_bf16(v01, pb1, oa, 0, 0, 0);
    ob = __builtin_amdgcn_mfma_f32_32x32x16_bf16(v10, pb0, ob, 0, 0, 0);
    ob = __builtin_amdgcn_mfma_f32_32x32x16_bf16(v11, pb1, ob, 0, 0, 0);
  }

  // ---- cross-wave combine (4 S-split partials) ----
  if (hi == 0) { mlb[w][0][qi] = m; mlb[w][1][qi] = l; }
  __syncthreads();
  float mm = fmaxf(fmaxf(mlb[0][0][qi], mlb[1][0][qi]),
                   fmaxf(mlb[2][0][qi], mlb[3][0][qi]));
  float Lt = 0.f;
#pragma unroll
  for (int sw = 0; sw < 4; ++sw)
    Lt += EXP2((mlb[sw][0][qi] - mm) * LOG2E) * mlb[sw][1][qi];
  float myf = EXP2((m - mm) * LOG2E);
  float inv = 1.0f / Lt;
#pragma unroll
  for (int r = 0; r < 16; ++r) {
    obuf[w][0][r][lane] = oa[r] * myf;
    obuf[w][1][r][lane] = ob[r] * myf;
  }
  __syncthreads();
  // wave w reduces d0 = w>>1, regs [(w&1)*8, +8); d = d0*32 + 8*(r>>2) + 4*hi + (r&3)
  const int d0 = w >> 1, rr = (w & 1) * 8;
  const int b = bh >> 3, h = bh & 7;
  float* orow = Out + ((b * Lc + q0 + qi) * Hc + h) * Dc;
#pragma unroll
  for (int t = 0; t < 2; ++t) {
    f32x4 acc;
#pragma unroll
    for (int j = 0; j < 4; ++j) {
      const int r = rr + 4 * t + j;
      acc[j] = (obuf[0][d0][r][lane] + obuf[1][d0][r][lane] +
                obuf[2][d0][r][lane] + obuf[3][d0][r][lane]) * inv;
    }
    const int dbase = d0 * 32 + ((rr + 4 * t) >> 2) * 8 + hi * 4;
    *reinterpret_cast<f32x4*>(orow + dbase) = acc;
  }
}

extern "C" void kernel_launch(void* const* d_in, const int* in_sizes, int n_in,
                              void* d_out, int out_size, void* d_ws, size_t ws_size,
                              hipStream_t stream) {
  const float* Q = (const float*)d_in[0];
  const float* K = (const float*)d_in[1];
  const float* V = (const float*)d_in[2];
  float* out = (float*)d_out;

  __hip_bfloat16* Qc = (__hip_bfloat16*)d_ws;
  __hip_bfloat16* Kc = Qc + ELEMS;
  __hip_bfloat16* Vt = Kc + ELEMS;

  cvt_qk_kernel<<<(2 * ELEMS / 4) / 256, 256, 0, stream>>>(Q, K, Qc, Kc);
  cvt_v_kernel<<<dim3(Sc / 64, BH), 64, 0, stream>>>(V, Vt);
  attn_kernel<<<dim3(1024), 256, 0, stream>>>(Qc, Kc, Vt, out);
}

// Round 4
// 49.905 us; speedup vs baseline: 2.6521x; 1.6000x over previous
//
#include <hip/hip_runtime.h>
#include <hip/hip_bf16.h>

// B=2, L=S=2048, H=8, E=D=64. Dense attention.
// out[b,l,h,d] = softmax_s( (1/8) * sum_e Q[b,l,h,e]K[b,s,h,e] ) @ V[b,s,h,d]

#define LOG2E 1.44269504088896340736f

#if __has_builtin(__builtin_amdgcn_exp2f)
#define EXP2(x) __builtin_amdgcn_exp2f(x)
#else
#define EXP2(x) exp2f(x)
#endif

typedef __attribute__((ext_vector_type(8))) short bf16x8;   // 8 bf16 = 4 VGPRs
typedef __attribute__((ext_vector_type(4))) float f32x4;
typedef __attribute__((ext_vector_type(16))) float f32x16;

static constexpr int Bc = 2, Lc = 2048, Sc = 2048, Hc = 8, Ec = 64, Dc = 64;
static constexpr int BH = Bc * Hc;                 // 16
static constexpr int ELEMS = Bc * Lc * Hc * Ec;    // 2097152 per tensor

static __device__ __forceinline__ unsigned short bfb(float x) {
  union { __hip_bfloat16 h; unsigned short u; } c;
  c.h = __float2bfloat16(x);
  return c.u;
}

// ---- Pass 1a: Q f32 [B,L,H,64] -> bf16 [B,H,L,64] row-major, pre-scaled by 0.125 ----
__global__ __launch_bounds__(256) void cvt_q_kernel(const float* __restrict__ Q,
                                                    __hip_bfloat16* __restrict__ Qc) {
  int t = blockIdx.x * 256 + threadIdx.x;   // ELEMS/4 threads
  int f = t * 4;                            // ((b*L + l)*H + h)*64 + e
  int e = f & 63;
  int h = (f >> 6) & 7;
  int l = (f >> 9) & 2047;
  int b = f >> 20;
  float4 v = *reinterpret_cast<const float4*>(Q + f);
  int o = (((b << 3) + h) * Lc + l) * 64 + e;
  ushort4 w;
  w.x = bfb(v.x * 0.125f);
  w.y = bfb(v.y * 0.125f);
  w.z = bfb(v.z * 0.125f);
  w.w = bfb(v.w * 0.125f);
  *reinterpret_cast<ushort4*>(Qc + o) = w;
}

// ---- Pass 1b: K f32 [B,S,H,64] -> bf16 FRAG-MAJOR ----
// Per head (bh): [kb=key/32][es=e/16][lane=hi*32+qi][j=0..7], 16B per lane slot:
//   elem offset = kb*2048 + es*512 + hi*256 + qi*8 + j  holds K[kb*32+qi][es*16+hi*8+j].
// Attention K-frag load is then base + kb*2048 + es*512 + lane*8 (fully coalesced 1KB).
__global__ __launch_bounds__(256) void cvt_k_kernel(const float* __restrict__ K,
                                                    __hip_bfloat16* __restrict__ Kc) {
  int t = blockIdx.x * 256 + threadIdx.x;   // ELEMS/8 threads
  int f = t * 8;                            // ((b*S + s)*H + h)*64 + e
  int e = f & 63;
  int h = (f >> 6) & 7;
  int s = (f >> 9) & 2047;
  int b = f >> 20;
  float4 v0 = *reinterpret_cast<const float4*>(K + f);
  float4 v1 = *reinterpret_cast<const float4*>(K + f + 4);
  int es = e >> 4, hi = (e >> 3) & 1;
  int kb = s >> 5, qi = s & 31;
  int o = ((b << 3) + h) * (Sc * 64) + kb * 2048 + es * 512 + hi * 256 + qi * 8;
  union { ushort u[8]; uint4 q; } pk;
  pk.u[0] = bfb(v0.x); pk.u[1] = bfb(v0.y); pk.u[2] = bfb(v0.z); pk.u[3] = bfb(v0.w);
  pk.u[4] = bfb(v1.x); pk.u[5] = bfb(v1.y); pk.u[6] = bfb(v1.z); pk.u[7] = bfb(v1.w);
  *reinterpret_cast<uint4*>(Kc + o) = pk.q;
}

// ---- Pass 2: V f32 [B,S,H,64] -> bf16 V^T FRAG-MAJOR ----
// Per head: [kb][d0=d/32][ks=k16slice][lane=hi*32+qi][j], 16B per lane slot:
//   elem offset = kb*2048 + d0*1024 + ks*512 + hi*256 + qi*8 + j
//   holds V[s = kb*32 + ks*16 + hi*8 + j][d = d0*32 + qi]  (i.e. Vt[d][s]).
__global__ __launch_bounds__(64) void cvt_v_kernel(const float* __restrict__ V,
                                                   __hip_bfloat16* __restrict__ Vt) {
  __shared__ __hip_bfloat16 tile[64][68];   // [s in tile][d], pad 68 -> conflict-free reads
  const int s0 = blockIdx.x * 64;
  const int bh = blockIdx.y;
  const int b = bh >> 3, h = bh & 7;
  const int lane = threadIdx.x;
#pragma unroll 4
  for (int j = 0; j < 64; ++j) {
    float v = V[((b * Sc + s0 + j) * Hc + h) * 64 + lane];  // coalesced 256B rows
    tile[j][lane] = __float2bfloat16(v);
  }
  __syncthreads();
  const int qi = lane & 31, hi = lane >> 5;
  __hip_bfloat16* Vb = Vt + bh * (Sc * 64);
#pragma unroll
  for (int kb2 = 0; kb2 < 2; ++kb2)
#pragma unroll
    for (int d0 = 0; d0 < 2; ++d0)
#pragma unroll
      for (int ks = 0; ks < 2; ++ks) {
        union { ushort u[8]; uint4 q; } pk;
#pragma unroll
        for (int j = 0; j < 8; ++j) {
          union { __hip_bfloat16 h; ushort u; } c;
          c.h = tile[kb2 * 32 + ks * 16 + hi * 8 + j][d0 * 32 + qi];
          pk.u[j] = c.u;
        }
        int o = ((s0 >> 5) + kb2) * 2048 + d0 * 1024 + ks * 512 + lane * 8;
        *reinterpret_cast<uint4*>(Vb + o) = pk.q;   // coalesced 1KB
      }
}

// permlane32_swap: after op, o0 = [a.lo | b.lo], o1 = [a.hi | b.hi] (half-row exchange)
static __device__ __forceinline__ void plswap(unsigned a, unsigned b,
                                              unsigned& o0, unsigned& o1, int hi) {
#if __has_builtin(__builtin_amdgcn_permlane32_swap)
  auto r = __builtin_amdgcn_permlane32_swap(a, b, false, false);
  o0 = r[0];
  o1 = r[1];
#else
  unsigned ax = (unsigned)__shfl_xor((int)a, 32);
  unsigned bx = (unsigned)__shfl_xor((int)b, 32);
  o0 = hi ? bx : a;
  o1 = hi ? b : ax;
#endif
}

static __device__ __forceinline__ unsigned pkbf(float a, float b) {
  union { __hip_bfloat162 h; unsigned u; } c;
  c.h = __float22bfloat162_rn(make_float2(a, b));  // -> v_cvt_pk_bf16_f32
  return c.u;
}

static __device__ __forceinline__ bf16x8 pack4(unsigned w0, unsigned w1,
                                               unsigned w2, unsigned w3) {
  union { unsigned u[4]; bf16x8 v; } c;
  c.u[0] = w0; c.u[1] = w1; c.u[2] = w2; c.u[3] = w3;
  return c.v;
}

// ---- Pass 3: flash attention, 32x32 swapped MFMA, frag-major coalesced loads ----
// Grid: 1024 blocks, XCD-pinned: each XCD owns 2 (b,h) heads (K/V 1MB -> L2-resident).
// Block: 4 waves share one 32-q-row tile; wave w handles keys s = w*32 + 128*t.
// All in-loop global loads are SGPR-base + imm + lane*16B (coalesced 1KB each).
__global__ __launch_bounds__(256, 4) void attn_kernel(const __hip_bfloat16* __restrict__ Qc,
                                                      const __hip_bfloat16* __restrict__ Kc,
                                                      const __hip_bfloat16* __restrict__ Vt,
                                                      float* __restrict__ Out) {
  __shared__ float obuf[4][2][16][64];  // [wave][d0][reg][lane] 32KB, conflict-free
  __shared__ float mlb[4][2][32];       // [wave][{m,l}][q]

  const int lid = blockIdx.x;           // 1024 = 8 xcd * 2 heads * 64 qtiles
  const int xcd = lid & 7;
  const int i = lid >> 3;
  const int bh = (xcd << 1) | (i >> 6);
  const int q0 = (i & 63) << 5;         // 32 q rows per block
  const int w = threadIdx.x >> 6;
  const int lane = threadIdx.x & 63;
  const int qi = lane & 31;             // this lane's q row
  const int hi = lane >> 5;

  const __hip_bfloat16* Qh = Qc + (bh * Lc + q0) * Ec;
  const __hip_bfloat16* Kh = Kc + bh * (Sc * 64);   // frag-major
  const __hip_bfloat16* Vh = Vt + bh * (Sc * 64);   // frag-major

  // Q B-frags (one-time, row-major scatter is fine): Q[q=qi][e = es*16 + hi*8 + j]
  bf16x8 qf0 = *reinterpret_cast<const bf16x8*>(Qh + qi * 64 + 0 * 16 + hi * 8);
  bf16x8 qf1 = *reinterpret_cast<const bf16x8*>(Qh + qi * 64 + 1 * 16 + hi * 8);
  bf16x8 qf2 = *reinterpret_cast<const bf16x8*>(Qh + qi * 64 + 2 * 16 + hi * 8);
  bf16x8 qf3 = *reinterpret_cast<const bf16x8*>(Qh + qi * 64 + 3 * 16 + hi * 8);

  f32x16 oa, ob;                         // O^T accum
#pragma unroll
  for (int r = 0; r < 16; ++r) { oa[r] = 0.f; ob[r] = 0.f; }
  float m = -1.0e30f, l = 0.f;

  for (int s = w * 32; s < Sc; s += 128) {
    const __hip_bfloat16* Kp = Kh + (s >> 5) * 2048 + lane * 8;
    bf16x8 k0 = *reinterpret_cast<const bf16x8*>(Kp + 0 * 512);
    bf16x8 k1 = *reinterpret_cast<const bf16x8*>(Kp + 1 * 512);
    bf16x8 k2 = *reinterpret_cast<const bf16x8*>(Kp + 2 * 512);
    bf16x8 k3 = *reinterpret_cast<const bf16x8*>(Kp + 3 * 512);
    const __hip_bfloat16* Vp = Vh + (s >> 5) * 2048 + lane * 8;
    bf16x8 v00 = *reinterpret_cast<const bf16x8*>(Vp + 0 * 512);
    bf16x8 v01 = *reinterpret_cast<const bf16x8*>(Vp + 1 * 512);
    bf16x8 v10 = *reinterpret_cast<const bf16x8*>(Vp + 2 * 512);
    bf16x8 v11 = *reinterpret_cast<const bf16x8*>(Vp + 3 * 512);

    f32x16 sc;
#pragma unroll
    for (int r = 0; r < 16; ++r) sc[r] = 0.f;
    __builtin_amdgcn_s_setprio(1);
    sc = __builtin_amdgcn_mfma_f32_32x32x16_bf16(k0, qf0, sc, 0, 0, 0);
    sc = __builtin_amdgcn_mfma_f32_32x32x16_bf16(k1, qf1, sc, 0, 0, 0);
    sc = __builtin_amdgcn_mfma_f32_32x32x16_bf16(k2, qf2, sc, 0, 0, 0);
    sc = __builtin_amdgcn_mfma_f32_32x32x16_bf16(k3, qf3, sc, 0, 0, 0);
    __builtin_amdgcn_s_setprio(0);

    // row max: in-lane tree + 1 permlane cross-half
    float x0 = fmaxf(fmaxf(sc[0], sc[1]), fmaxf(sc[2], sc[3]));
    float x1 = fmaxf(fmaxf(sc[4], sc[5]), fmaxf(sc[6], sc[7]));
    float x2 = fmaxf(fmaxf(sc[8], sc[9]), fmaxf(sc[10], sc[11]));
    float x3 = fmaxf(fmaxf(sc[12], sc[13]), fmaxf(sc[14], sc[15]));
    float mx = fmaxf(fmaxf(x0, x1), fmaxf(x2, x3));
    unsigned ua, ub;
    plswap(__float_as_uint(mx), __float_as_uint(mx), ua, ub, hi);
    mx = fmaxf(__uint_as_float(ua), __uint_as_float(ub));

    // defer-max (T13): only rescale when running max grew by > 8
    if (__any(mx > m + 8.0f)) {
      float mnew = fmaxf(m, mx);
      float corr = EXP2((m - mnew) * LOG2E);
      l *= corr;
#pragma unroll
      for (int r = 0; r < 16; ++r) { oa[r] *= corr; ob[r] *= corr; }
      m = mnew;
    }

#pragma unroll
    for (int r = 0; r < 16; ++r) sc[r] = EXP2((sc[r] - m) * LOG2E);

    float r0 = (sc[0] + sc[1]) + (sc[2] + sc[3]);
    float r1 = (sc[4] + sc[5]) + (sc[6] + sc[7]);
    float r2 = (sc[8] + sc[9]) + (sc[10] + sc[11]);
    float r3 = (sc[12] + sc[13]) + (sc[14] + sc[15]);
    float rs = (r0 + r1) + (r2 + r3);
    plswap(__float_as_uint(rs), __float_as_uint(rs), ua, ub, hi);
    rs = __uint_as_float(ua) + __uint_as_float(ub);
    l += rs;

    // P^T B-frags via cvt_pk + permlane32_swap (T12)
    unsigned c0, c1, c2, c3, w0, w1, w2, w3;
    c0 = pkbf(sc[0], sc[1]);  c1 = pkbf(sc[4], sc[5]);
    c2 = pkbf(sc[2], sc[3]);  c3 = pkbf(sc[6], sc[7]);
    plswap(c0, c1, w0, w2, hi);
    plswap(c2, c3, w1, w3, hi);
    bf16x8 pb0 = pack4(w0, w1, w2, w3);
    c0 = pkbf(sc[8], sc[9]);   c1 = pkbf(sc[12], sc[13]);
    c2 = pkbf(sc[10], sc[11]); c3 = pkbf(sc[14], sc[15]);
    plswap(c0, c1, w0, w2, hi);
    plswap(c2, c3, w1, w3, hi);
    bf16x8 pb1 = pack4(w0, w1, w2, w3);

    __builtin_amdgcn_s_setprio(1);
    oa = __builtin_amdgcn_mfma_f32_32x32x16_bf16(v00, pb0, oa, 0, 0, 0);
    oa = __builtin_amdgcn_mfma_f32_32x32x16_bf16(v01, pb1, oa, 0, 0, 0);
    ob = __builtin_amdgcn_mfma_f32_32x32x16_bf16(v10, pb0, ob, 0, 0, 0);
    ob = __builtin_amdgcn_mfma_f32_32x32x16_bf16(v11, pb1, ob, 0, 0, 0);
    __builtin_amdgcn_s_setprio(0);
  }

  // ---- cross-wave combine (4 S-split partials) ----
  if (hi == 0) { mlb[w][0][qi] = m; mlb[w][1][qi] = l; }
  __syncthreads();
  float mm = fmaxf(fmaxf(mlb[0][0][qi], mlb[1][0][qi]),
                   fmaxf(mlb[2][0][qi], mlb[3][0][qi]));
  float Lt = 0.f;
#pragma unroll
  for (int sw = 0; sw < 4; ++sw)
    Lt += EXP2((mlb[sw][0][qi] - mm) * LOG2E) * mlb[sw][1][qi];
  float myf = EXP2((m - mm) * LOG2E);
  float inv = 1.0f / Lt;
#pragma unroll
  for (int r = 0; r < 16; ++r) {
    obuf[w][0][r][lane] = oa[r] * myf;
    obuf[w][1][r][lane] = ob[r] * myf;
  }
  __syncthreads();
  // wave w reduces d0 = w>>1, regs [(w&1)*8, +8); d = d0*32 + 8*(r>>2) + 4*hi + (r&3)
  const int d0 = w >> 1, rr = (w & 1) * 8;
  const int b = bh >> 3, h = bh & 7;
  float* orow = Out + ((b * Lc + q0 + qi) * Hc + h) * Dc;
#pragma unroll
  for (int t = 0; t < 2; ++t) {
    f32x4 acc;
#pragma unroll
    for (int j = 0; j < 4; ++j) {
      const int r = rr + 4 * t + j;
      acc[j] = (obuf[0][d0][r][lane] + obuf[1][d0][r][lane] +
                obuf[2][d0][r][lane] + obuf[3][d0][r][lane]) * inv;
    }
    const int dbase = d0 * 32 + ((rr + 4 * t) >> 2) * 8 + hi * 4;
    *reinterpret_cast<f32x4*>(orow + dbase) = acc;
  }
}

extern "C" void kernel_launch(void* const* d_in, const int* in_sizes, int n_in,
                              void* d_out, int out_size, void* d_ws, size_t ws_size,
                              hipStream_t stream) {
  const float* Q = (const float*)d_in[0];
  const float* K = (const float*)d_in[1];
  const float* V = (const float*)d_in[2];
  float* out = (float*)d_out;

  __hip_bfloat16* Qc = (__hip_bfloat16*)d_ws;
  __hip_bfloat16* Kc = Qc + ELEMS;
  __hip_bfloat16* Vt = Kc + ELEMS;

  cvt_q_kernel<<<(ELEMS / 4) / 256, 256, 0, stream>>>(Q, Qc);
  cvt_k_kernel<<<(ELEMS / 8) / 256, 256, 0, stream>>>(K, Kc);
  cvt_v_kernel<<<dim3(Sc / 64, BH), 64, 0, stream>>>(V, Vt);
  attn_kernel<<<dim3(1024), 256, 0, stream>>>(Qc, Kc, Vt, out);
}

// Round 5
// 46.382 us; speedup vs baseline: 2.8536x; 1.0760x over previous
//
#include <hip/hip_runtime.h>
#include <hip/hip_bf16.h>

// B=2, L=S=2048, H=8, E=D=64. Dense attention.
// out[b,l,h,d] = softmax_s( (1/8) * sum_e Q[b,l,h,e]K[b,s,h,e] ) @ V[b,s,h,d]

#define LOG2E 1.44269504088896340736f
#define SCL2 0.18033688011112042f   // 0.125 * LOG2E (scale folded into exp2 argument)

#if __has_builtin(__builtin_amdgcn_exp2f)
#define EXP2(x) __builtin_amdgcn_exp2f(x)
#else
#define EXP2(x) exp2f(x)
#endif

typedef __attribute__((ext_vector_type(8))) short bf16x8;   // 8 bf16 = 4 VGPRs
typedef __attribute__((ext_vector_type(4))) float f32x4;
typedef __attribute__((ext_vector_type(16))) float f32x16;

static constexpr int Bc = 2, Lc = 2048, Sc = 2048, Hc = 8, Ec = 64, Dc = 64;
static constexpr int BH = Bc * Hc;                 // 16
static constexpr int ELEMS = Bc * Lc * Hc * Ec;    // 2097152 per tensor

static __device__ __forceinline__ unsigned short bfb(float x) {
  union { __hip_bfloat16 h; unsigned short u; } c;
  c.h = __float2bfloat16(x);
  return c.u;
}
static __device__ __forceinline__ unsigned pkbf(float a, float b) {
  union { __hip_bfloat162 h; unsigned u; } c;
  c.h = __float22bfloat162_rn(make_float2(a, b));  // -> v_cvt_pk_bf16_f32
  return c.u;
}
static __device__ __forceinline__ bf16x8 pack4(unsigned w0, unsigned w1,
                                               unsigned w2, unsigned w3) {
  union { unsigned u[4]; bf16x8 v; } c;
  c.u[0] = w0; c.u[1] = w1; c.u[2] = w2; c.u[3] = w3;
  return c.v;
}

// permlane32_swap: o0 = [a.lo | b.lo], o1 = [a.hi | b.hi] (lane<32 / lane>=32 exchange)
static __device__ __forceinline__ void plswap(unsigned a, unsigned b,
                                              unsigned& o0, unsigned& o1, int hi) {
#if __has_builtin(__builtin_amdgcn_permlane32_swap)
  auto r = __builtin_amdgcn_permlane32_swap(a, b, false, false);
  o0 = r[0];
  o1 = r[1];
#else
  unsigned ax = (unsigned)__shfl_xor((int)a, 32);
  unsigned bx = (unsigned)__shfl_xor((int)b, 32);
  o0 = hi ? bx : a;
  o1 = hi ? b : ax;
#endif
}

// ---- Fused prepass: K -> frag-major bf16, V -> transposed frag-major bf16 ----
// K frag-major per head: elem off = kb*2048 + es*512 + hi*256 + qi*8 + j
//   holds K[kb*32+qi][es*16+hi*8+j]; attn load = base + kb*2048 + es*512 + lane*8.
// V frag-major per head: elem off = kb*2048 + d0*1024 + ks*512 + hi*256 + qi*8 + j
//   holds V[kb*32 + ks*16 + hi*8 + j][d0*32 + qi]  (V^T fragments).
__global__ __launch_bounds__(256) void prep_kv_kernel(const float* __restrict__ K,
                                                      const float* __restrict__ V,
                                                      __hip_bfloat16* __restrict__ Kc,
                                                      __hip_bfloat16* __restrict__ Vt) {
  __shared__ __hip_bfloat16 tile[4][64][68];   // per-wave V transpose tile (padded)
  if (blockIdx.x < 1024) {
    // ---- K section: pointwise relayout, 8 elems/thread ----
    int t = blockIdx.x * 256 + threadIdx.x;    // ELEMS/8 threads
    int f = t * 8;                             // ((b*S + s)*H + h)*64 + e
    int e = f & 63;
    int h = (f >> 6) & 7;
    int s = (f >> 9) & 2047;
    int b = f >> 20;
    float4 v0 = *reinterpret_cast<const float4*>(K + f);
    float4 v1 = *reinterpret_cast<const float4*>(K + f + 4);
    int es = e >> 4, hi = (e >> 3) & 1;
    int kb = s >> 5, qi = s & 31;
    int o = ((b << 3) + h) * (Sc * 64) + kb * 2048 + es * 512 + hi * 256 + qi * 8;
    union { ushort u[8]; uint4 q; } pk;
    pk.u[0] = bfb(v0.x); pk.u[1] = bfb(v0.y); pk.u[2] = bfb(v0.z); pk.u[3] = bfb(v0.w);
    pk.u[4] = bfb(v1.x); pk.u[5] = bfb(v1.y); pk.u[6] = bfb(v1.z); pk.u[7] = bfb(v1.w);
    *reinterpret_cast<uint4*>(Kc + o) = pk.q;
  } else {
    // ---- V section: 4 waves, each transposes one 64-key tile of one head ----
    const int w = threadIdx.x >> 6;
    const int lane = threadIdx.x & 63;
    const int task = (blockIdx.x - 1024) * 4 + w;  // 512 tasks = 32 s-tiles x 16 heads
    const int st = task & 31;
    const int bh = task >> 5;
    const int s0 = st * 64;
    const int b = bh >> 3, h = bh & 7;
#pragma unroll 4
    for (int j = 0; j < 64; ++j) {
      float v = V[((b * Sc + s0 + j) * Hc + h) * 64 + lane];  // coalesced 256B rows
      tile[w][j][lane] = __float2bfloat16(v);
    }
    __syncthreads();
    const int qi = lane & 31, hi = lane >> 5;
    __hip_bfloat16* Vb = Vt + bh * (Sc * 64);
#pragma unroll
    for (int kb2 = 0; kb2 < 2; ++kb2)
#pragma unroll
      for (int d0 = 0; d0 < 2; ++d0)
#pragma unroll
        for (int ks = 0; ks < 2; ++ks) {
          union { ushort u[8]; uint4 q; } pk;
#pragma unroll
          for (int j = 0; j < 8; ++j) {
            union { __hip_bfloat16 h; ushort u; } c;
            c.h = tile[w][kb2 * 32 + ks * 16 + hi * 8 + j][d0 * 32 + qi];
            pk.u[j] = c.u;
          }
          int o = ((s0 >> 5) + kb2) * 2048 + d0 * 1024 + ks * 512 + lane * 8;
          *reinterpret_cast<uint4*>(Vb + o) = pk.q;   // coalesced 1KB
        }
  }
}

// online-softmax for one q-group: raw scores (unscaled); scale folded into exp2 arg.
static __device__ __forceinline__ void sm_group(f32x16& sc, float& m, float& l,
                                                f32x16& oA, f32x16& oB, int hi,
                                                bf16x8& pb0, bf16x8& pb1) {
  float x0 = fmaxf(fmaxf(sc[0], sc[1]), fmaxf(sc[2], sc[3]));
  float x1 = fmaxf(fmaxf(sc[4], sc[5]), fmaxf(sc[6], sc[7]));
  float x2 = fmaxf(fmaxf(sc[8], sc[9]), fmaxf(sc[10], sc[11]));
  float x3 = fmaxf(fmaxf(sc[12], sc[13]), fmaxf(sc[14], sc[15]));
  float mx = fmaxf(fmaxf(x0, x1), fmaxf(x2, x3));
  unsigned ua, ub;
  plswap(__float_as_uint(mx), __float_as_uint(mx), ua, ub, hi);
  mx = fmaxf(__uint_as_float(ua), __uint_as_float(ub));

  // defer-max (T13): 64 raw units = 8 nats (P bounded by e^8)
  if (__any(mx > m + 64.0f)) {
    float mnew = fmaxf(m, mx);
    float corr = EXP2((m - mnew) * SCL2);
    l *= corr;
#pragma unroll
    for (int r = 0; r < 16; ++r) { oA[r] *= corr; oB[r] *= corr; }
    m = mnew;
  }
  float mL = m * SCL2;
#pragma unroll
  for (int r = 0; r < 16; ++r) sc[r] = EXP2(sc[r] * SCL2 - mL);  // fma + exp

  float r0 = (sc[0] + sc[1]) + (sc[2] + sc[3]);
  float r1 = (sc[4] + sc[5]) + (sc[6] + sc[7]);
  float r2 = (sc[8] + sc[9]) + (sc[10] + sc[11]);
  float r3 = (sc[12] + sc[13]) + (sc[14] + sc[15]);
  float rs = (r0 + r1) + (r2 + r3);
  plswap(__float_as_uint(rs), __float_as_uint(rs), ua, ub, hi);
  rs = __uint_as_float(ua) + __uint_as_float(ub);
  l += rs;

  // P^T B-frags via cvt_pk + permlane32_swap (T12)
  unsigned c0, c1, c2, c3, y0, y1, y2, y3;
  c0 = pkbf(sc[0], sc[1]);  c1 = pkbf(sc[4], sc[5]);
  c2 = pkbf(sc[2], sc[3]);  c3 = pkbf(sc[6], sc[7]);
  plswap(c0, c1, y0, y2, hi);
  plswap(c2, c3, y1, y3, hi);
  pb0 = pack4(y0, y1, y2, y3);
  c0 = pkbf(sc[8], sc[9]);   c1 = pkbf(sc[12], sc[13]);
  c2 = pkbf(sc[10], sc[11]); c3 = pkbf(sc[14], sc[15]);
  plswap(c0, c1, y0, y2, hi);
  plswap(c2, c3, y1, y3, hi);
  pb1 = pack4(y0, y1, y2, y3);
}

// ---- Attention: 32x32 swapped MFMA, 64 q-rows/wave (2 q-groups), S-split x4 ----
// Grid: 512 blocks = 8 XCD x 2 heads x 32 q-tiles(64 rows). K/V 1MB/XCD -> L2-resident.
// Per iter: 8 coalesced loads serve 16 MFMAs (2 q-groups share K/V frags).
__global__ __launch_bounds__(256, 2) void attn_kernel(const float* __restrict__ Qf,
                                                      const __hip_bfloat16* __restrict__ Kc,
                                                      const __hip_bfloat16* __restrict__ Vt,
                                                      float* __restrict__ Out) {
  __shared__ float obuf[4][2][16][64];  // [wave][d0][reg][lane] 32KB, reused per q-group
  __shared__ float mlb[2][4][2][32];    // [group][wave][{m,l}][q]

  const int lid = blockIdx.x;           // 512 = 8 xcd * 2 heads * 32 qtiles
  const int xcd = lid & 7;
  const int i = lid >> 3;               // 0..63
  const int bh = (xcd << 1) | (i >> 5);
  const int q0 = (i & 31) << 6;         // 64 q rows per block
  const int w = threadIdx.x >> 6;
  const int lane = threadIdx.x & 63;
  const int qi = lane & 31;
  const int hi = lane >> 5;
  const int b = bh >> 3, h = bh & 7;

  const __hip_bfloat16* Kh = Kc + bh * (Sc * 64);   // frag-major
  const __hip_bfloat16* Vh = Vt + bh * (Sc * 64);   // frag-major

  // Q frags straight from f32 input (no prepass, no scaling — folded into exp2):
  // qf[g][es] holds Q[b, q0+g*32+qi, h, es*16+hi*8+j]
  bf16x8 qf[2][4];
#pragma unroll
  for (int g = 0; g < 2; ++g) {
    const float* qrow = Qf + ((b * Lc + q0 + g * 32 + qi) * Hc + h) * 64 + hi * 8;
#pragma unroll
    for (int es = 0; es < 4; ++es) {
      float4 a = *reinterpret_cast<const float4*>(qrow + es * 16);
      float4 c = *reinterpret_cast<const float4*>(qrow + es * 16 + 4);
      qf[g][es] = pack4(pkbf(a.x, a.y), pkbf(a.z, a.w), pkbf(c.x, c.y), pkbf(c.z, c.w));
    }
  }

  f32x16 oa0, ob0, oa1, ob1;
#pragma unroll
  for (int r = 0; r < 16; ++r) { oa0[r] = 0.f; ob0[r] = 0.f; oa1[r] = 0.f; ob1[r] = 0.f; }
  float m0 = -1.0e30f, l0 = 0.f, m1 = -1.0e30f, l1 = 0.f;

  for (int s = w * 32; s < Sc; s += 128) {
    const __hip_bfloat16* Kp = Kh + (s >> 5) * 2048 + lane * 8;
    bf16x8 k0 = *reinterpret_cast<const bf16x8*>(Kp + 0 * 512);
    bf16x8 k1 = *reinterpret_cast<const bf16x8*>(Kp + 1 * 512);
    bf16x8 k2 = *reinterpret_cast<const bf16x8*>(Kp + 2 * 512);
    bf16x8 k3 = *reinterpret_cast<const bf16x8*>(Kp + 3 * 512);
    const __hip_bfloat16* Vp = Vh + (s >> 5) * 2048 + lane * 8;
    bf16x8 v00 = *reinterpret_cast<const bf16x8*>(Vp + 0 * 512);
    bf16x8 v01 = *reinterpret_cast<const bf16x8*>(Vp + 1 * 512);
    bf16x8 v10 = *reinterpret_cast<const bf16x8*>(Vp + 2 * 512);
    bf16x8 v11 = *reinterpret_cast<const bf16x8*>(Vp + 3 * 512);

    f32x16 sc0, sc1;
#pragma unroll
    for (int r = 0; r < 16; ++r) { sc0[r] = 0.f; sc1[r] = 0.f; }
    __builtin_amdgcn_s_setprio(1);
    sc0 = __builtin_amdgcn_mfma_f32_32x32x16_bf16(k0, qf[0][0], sc0, 0, 0, 0);
    sc0 = __builtin_amdgcn_mfma_f32_32x32x16_bf16(k1, qf[0][1], sc0, 0, 0, 0);
    sc0 = __builtin_amdgcn_mfma_f32_32x32x16_bf16(k2, qf[0][2], sc0, 0, 0, 0);
    sc0 = __builtin_amdgcn_mfma_f32_32x32x16_bf16(k3, qf[0][3], sc0, 0, 0, 0);
    sc1 = __builtin_amdgcn_mfma_f32_32x32x16_bf16(k0, qf[1][0], sc1, 0, 0, 0);
    sc1 = __builtin_amdgcn_mfma_f32_32x32x16_bf16(k1, qf[1][1], sc1, 0, 0, 0);
    sc1 = __builtin_amdgcn_mfma_f32_32x32x16_bf16(k2, qf[1][2], sc1, 0, 0, 0);
    sc1 = __builtin_amdgcn_mfma_f32_32x32x16_bf16(k3, qf[1][3], sc1, 0, 0, 0);
    __builtin_amdgcn_s_setprio(0);

    bf16x8 pb0, pb1;
    sm_group(sc0, m0, l0, oa0, ob0, hi, pb0, pb1);
    __builtin_amdgcn_s_setprio(1);
    oa0 = __builtin_amdgcn_mfma_f32_32x32x16_bf16(v00, pb0, oa0, 0, 0, 0);
    oa0 = __builtin_amdgcn_mfma_f32_32x32x16_bf16(v01, pb1, oa0, 0, 0, 0);
    ob0 = __builtin_amdgcn_mfma_f32_32x32x16_bf16(v10, pb0, ob0, 0, 0, 0);
    ob0 = __builtin_amdgcn_mfma_f32_32x32x16_bf16(v11, pb1, ob0, 0, 0, 0);
    __builtin_amdgcn_s_setprio(0);

    sm_group(sc1, m1, l1, oa1, ob1, hi, pb0, pb1);
    __builtin_amdgcn_s_setprio(1);
    oa1 = __builtin_amdgcn_mfma_f32_32x32x16_bf16(v00, pb0, oa1, 0, 0, 0);
    oa1 = __builtin_amdgcn_mfma_f32_32x32x16_bf16(v01, pb1, oa1, 0, 0, 0);
    ob1 = __builtin_amdgcn_mfma_f32_32x32x16_bf16(v10, pb0, ob1, 0, 0, 0);
    ob1 = __builtin_amdgcn_mfma_f32_32x32x16_bf16(v11, pb1, ob1, 0, 0, 0);
    __builtin_amdgcn_s_setprio(0);
  }

  // ---- cross-wave combine (4 S-split partials), per q-group through shared obuf ----
  if (hi == 0) {
    mlb[0][w][0][qi] = m0; mlb[0][w][1][qi] = l0;
    mlb[1][w][0][qi] = m1; mlb[1][w][1][qi] = l1;
  }
  __syncthreads();
  float myf[2], inv[2];
#pragma unroll
  for (int g = 0; g < 2; ++g) {
    float mm = fmaxf(fmaxf(mlb[g][0][0][qi], mlb[g][1][0][qi]),
                     fmaxf(mlb[g][2][0][qi], mlb[g][3][0][qi]));
    float Lt = 0.f;
#pragma unroll
    for (int sw = 0; sw < 4; ++sw)
      Lt += EXP2((mlb[g][sw][0][qi] - mm) * SCL2) * mlb[g][sw][1][qi];
    float mreg = g ? m1 : m0;
    myf[g] = EXP2((mreg - mm) * SCL2);
    inv[g] = 1.0f / Lt;
  }
  const int d0 = w >> 1, rr = (w & 1) * 8;
#pragma unroll
  for (int g = 0; g < 2; ++g) {
    if (g) __syncthreads();
    const f32x16& A = g ? oa1 : oa0;
    const f32x16& Bv = g ? ob1 : ob0;
#pragma unroll
    for (int r = 0; r < 16; ++r) {
      obuf[w][0][r][lane] = A[r] * myf[g];
      obuf[w][1][r][lane] = Bv[r] * myf[g];
    }
    __syncthreads();
    float* orow = Out + ((b * Lc + q0 + g * 32 + qi) * Hc + h) * Dc;
#pragma unroll
    for (int t = 0; t < 2; ++t) {
      f32x4 acc;
#pragma unroll
      for (int j = 0; j < 4; ++j) {
        const int r = rr + 4 * t + j;
        acc[j] = (obuf[0][d0][r][lane] + obuf[1][d0][r][lane] +
                  obuf[2][d0][r][lane] + obuf[3][d0][r][lane]) * inv[g];
      }
      const int dbase = d0 * 32 + ((rr + 4 * t) >> 2) * 8 + hi * 4;
      *reinterpret_cast<f32x4*>(orow + dbase) = acc;
    }
  }
}

extern "C" void kernel_launch(void* const* d_in, const int* in_sizes, int n_in,
                              void* d_out, int out_size, void* d_ws, size_t ws_size,
                              hipStream_t stream) {
  const float* Q = (const float*)d_in[0];
  const float* K = (const float*)d_in[1];
  const float* V = (const float*)d_in[2];
  float* out = (float*)d_out;

  __hip_bfloat16* Kc = (__hip_bfloat16*)d_ws;       // 4 MiB
  __hip_bfloat16* Vt = Kc + ELEMS;                   // 4 MiB

  // fused prepass: blocks [0,1024) K relayout, [1024,1152) V transpose
  prep_kv_kernel<<<dim3(1152), 256, 0, stream>>>(K, V, Kc, Vt);
  // attention: 512 blocks = 8 XCD x 2 heads x 32 q-tiles (64 rows each)
  attn_kernel<<<dim3(512), 256, 0, stream>>>(Q, Kc, Vt, out);
}

// Round 6
// 43.814 us; speedup vs baseline: 3.0208x; 1.0586x over previous
//
#include <hip/hip_runtime.h>
#include <hip/hip_bf16.h>

// B=2, L=S=2048, H=8, E=D=64. Dense attention.
// out[b,l,h,d] = softmax_s( (1/8) * sum_e Q[b,l,h,e]K[b,s,h,e] ) @ V[b,s,h,d]

#define LOG2E 1.44269504088896340736f
#define SCL2 0.18033688011112042f   // 0.125 * LOG2E (scale folded into exp2 argument)

#if __has_builtin(__builtin_amdgcn_exp2f)
#define EXP2(x) __builtin_amdgcn_exp2f(x)
#else
#define EXP2(x) exp2f(x)
#endif

typedef __attribute__((ext_vector_type(8))) short bf16x8;   // 8 bf16 = 4 VGPRs
typedef __attribute__((ext_vector_type(4))) float f32x4;
typedef __attribute__((ext_vector_type(16))) float f32x16;

static constexpr int Bc = 2, Lc = 2048, Sc = 2048, Hc = 8, Ec = 64, Dc = 64;
static constexpr int BH = Bc * Hc;                 // 16
static constexpr int ELEMS = Bc * Lc * Hc * Ec;    // 2097152 per tensor

static __device__ __forceinline__ unsigned short bfb(float x) {
  union { __hip_bfloat16 h; unsigned short u; } c;
  c.h = __float2bfloat16(x);
  return c.u;
}
static __device__ __forceinline__ unsigned pkbf(float a, float b) {
  union { __hip_bfloat162 h; unsigned u; } c;
  c.h = __float22bfloat162_rn(make_float2(a, b));  // -> v_cvt_pk_bf16_f32
  return c.u;
}
static __device__ __forceinline__ bf16x8 pack4(unsigned w0, unsigned w1,
                                               unsigned w2, unsigned w3) {
  union { unsigned u[4]; bf16x8 v; } c;
  c.u[0] = w0; c.u[1] = w1; c.u[2] = w2; c.u[3] = w3;
  return c.v;
}

// permlane32_swap: o0 = [a.lo | b.lo], o1 = [a.hi | b.hi] (lane<32 / lane>=32 exchange)
static __device__ __forceinline__ void plswap(unsigned a, unsigned b,
                                              unsigned& o0, unsigned& o1, int hi) {
#if __has_builtin(__builtin_amdgcn_permlane32_swap)
  auto r = __builtin_amdgcn_permlane32_swap(a, b, false, false);
  o0 = r[0];
  o1 = r[1];
#else
  unsigned ax = (unsigned)__shfl_xor((int)a, 32);
  unsigned bx = (unsigned)__shfl_xor((int)b, 32);
  o0 = hi ? bx : a;
  o1 = hi ? b : ax;
#endif
}
static __device__ __forceinline__ float cross_half_max(float x, int hi) {
  unsigned ua, ub;
  plswap(__float_as_uint(x), __float_as_uint(x), ua, ub, hi);
  return fmaxf(__uint_as_float(ua), __uint_as_float(ub));
}
static __device__ __forceinline__ float cross_half_sum(float x, int hi) {
  unsigned ua, ub;
  plswap(__float_as_uint(x), __float_as_uint(x), ua, ub, hi);
  return __uint_as_float(ua) + __uint_as_float(ub);
}

// ---- Fused prepass: K -> frag-major bf16, V -> transposed frag-major bf16 ----
__global__ __launch_bounds__(256) void prep_kv_kernel(const float* __restrict__ K,
                                                      const float* __restrict__ V,
                                                      __hip_bfloat16* __restrict__ Kc,
                                                      __hip_bfloat16* __restrict__ Vt) {
  __shared__ __hip_bfloat16 tile[4][64][68];   // per-wave V transpose tile (padded)
  if (blockIdx.x < 1024) {
    // ---- K section: pointwise relayout, 8 elems/thread ----
    int t = blockIdx.x * 256 + threadIdx.x;    // ELEMS/8 threads
    int f = t * 8;                             // ((b*S + s)*H + h)*64 + e
    int e = f & 63;
    int h = (f >> 6) & 7;
    int s = (f >> 9) & 2047;
    int b = f >> 20;
    float4 v0 = *reinterpret_cast<const float4*>(K + f);
    float4 v1 = *reinterpret_cast<const float4*>(K + f + 4);
    int es = e >> 4, hi = (e >> 3) & 1;
    int kb = s >> 5, qi = s & 31;
    int o = ((b << 3) + h) * (Sc * 64) + kb * 2048 + es * 512 + hi * 256 + qi * 8;
    union { ushort u[8]; uint4 q; } pk;
    pk.u[0] = bfb(v0.x); pk.u[1] = bfb(v0.y); pk.u[2] = bfb(v0.z); pk.u[3] = bfb(v0.w);
    pk.u[4] = bfb(v1.x); pk.u[5] = bfb(v1.y); pk.u[6] = bfb(v1.z); pk.u[7] = bfb(v1.w);
    *reinterpret_cast<uint4*>(Kc + o) = pk.q;
  } else {
    // ---- V section: 4 waves, each transposes one 64-key tile of one head ----
    const int w = threadIdx.x >> 6;
    const int lane = threadIdx.x & 63;
    const int task = (blockIdx.x - 1024) * 4 + w;  // 512 tasks = 32 s-tiles x 16 heads
    const int st = task & 31;
    const int bh = task >> 5;
    const int s0 = st * 64;
    const int b = bh >> 3, h = bh & 7;
#pragma unroll 4
    for (int j = 0; j < 64; ++j) {
      float v = V[((b * Sc + s0 + j) * Hc + h) * 64 + lane];  // coalesced 256B rows
      tile[w][j][lane] = __float2bfloat16(v);
    }
    __syncthreads();
    const int qi = lane & 31, hi = lane >> 5;
    __hip_bfloat16* Vb = Vt + bh * (Sc * 64);
#pragma unroll
    for (int kb2 = 0; kb2 < 2; ++kb2)
#pragma unroll
      for (int d0 = 0; d0 < 2; ++d0)
#pragma unroll
        for (int ks = 0; ks < 2; ++ks) {
          union { ushort u[8]; uint4 q; } pk;
#pragma unroll
          for (int j = 0; j < 8; ++j) {
            union { __hip_bfloat16 h; ushort u; } c;
            c.h = tile[w][kb2 * 32 + ks * 16 + hi * 8 + j][d0 * 32 + qi];
            pk.u[j] = c.u;
          }
          int o = ((s0 >> 5) + kb2) * 2048 + d0 * 1024 + ks * 512 + lane * 8;
          *reinterpret_cast<uint4*>(Vb + o) = pk.q;   // coalesced 1KB
        }
  }
}

// online-softmax for one q-group. l is a PER-HALF-LANE partial (combined after loop);
// max permlane only on the (rare) rescale path.
static __device__ __forceinline__ void sm_group(f32x16& sc, float& m, float& l,
                                                f32x16& oA, f32x16& oB, int hi,
                                                bf16x8& pb0, bf16x8& pb1) {
  float x0 = fmaxf(fmaxf(sc[0], sc[1]), fmaxf(sc[2], sc[3]));
  float x1 = fmaxf(fmaxf(sc[4], sc[5]), fmaxf(sc[6], sc[7]));
  float x2 = fmaxf(fmaxf(sc[8], sc[9]), fmaxf(sc[10], sc[11]));
  float x3 = fmaxf(fmaxf(sc[12], sc[13]), fmaxf(sc[14], sc[15]));
  float mx = fmaxf(fmaxf(x0, x1), fmaxf(x2, x3));   // lane-local 16-key max

  // defer-max (T13): 64 raw units = 8 nats (P bounded by e^8). Cross-half max only here.
  if (__any(mx > m + 64.0f)) {
    float mrow = cross_half_max(mx, hi);
    float mnew = fmaxf(m, mrow);
    float corr = EXP2((m - mnew) * SCL2);
    l *= corr;
#pragma unroll
    for (int r = 0; r < 16; ++r) { oA[r] *= corr; oB[r] *= corr; }
    m = mnew;
  }
  float mL = m * SCL2;
#pragma unroll
  for (int r = 0; r < 16; ++r) sc[r] = EXP2(sc[r] * SCL2 - mL);  // fma + exp

  float r0 = (sc[0] + sc[1]) + (sc[2] + sc[3]);
  float r1 = (sc[4] + sc[5]) + (sc[6] + sc[7]);
  float r2 = (sc[8] + sc[9]) + (sc[10] + sc[11]);
  float r3 = (sc[12] + sc[13]) + (sc[14] + sc[15]);
  l += (r0 + r1) + (r2 + r3);                       // per-half partial, no permlane

  // P^T B-frags via cvt_pk + permlane32_swap (T12)
  unsigned c0, c1, c2, c3, y0, y1, y2, y3;
  c0 = pkbf(sc[0], sc[1]);  c1 = pkbf(sc[4], sc[5]);
  c2 = pkbf(sc[2], sc[3]);  c3 = pkbf(sc[6], sc[7]);
  plswap(c0, c1, y0, y2, hi);
  plswap(c2, c3, y1, y3, hi);
  pb0 = pack4(y0, y1, y2, y3);
  c0 = pkbf(sc[8], sc[9]);   c1 = pkbf(sc[12], sc[13]);
  c2 = pkbf(sc[10], sc[11]); c3 = pkbf(sc[14], sc[15]);
  plswap(c0, c1, y0, y2, hi);
  plswap(c2, c3, y1, y3, hi);
  pb1 = pack4(y0, y1, y2, y3);
}

// ---- Attention: 32x32 swapped MFMA, 64 q-rows/wave, 1-deep K/V register pipeline ----
// Grid: 512 blocks = 8 XCD x 2 heads x 32 q-tiles(64 rows). K/V 1MB/XCD -> L2-resident.
__global__ __launch_bounds__(256, 2) void attn_kernel(const float* __restrict__ Qf,
                                                      const __hip_bfloat16* __restrict__ Kc,
                                                      const __hip_bfloat16* __restrict__ Vt,
                                                      float* __restrict__ Out) {
  __shared__ float obuf[4][2][16][64];  // [wave][d0][reg][lane] 32KB, reused per q-group
  __shared__ float mlb[2][4][2][32];    // [group][wave][{m,l}][q]

  const int lid = blockIdx.x;           // 512 = 8 xcd * 2 heads * 32 qtiles
  const int xcd = lid & 7;
  const int i = lid >> 3;               // 0..63
  const int bh = (xcd << 1) | (i >> 5);
  const int q0 = (i & 31) << 6;         // 64 q rows per block
  const int w = threadIdx.x >> 6;
  const int lane = threadIdx.x & 63;
  const int qi = lane & 31;
  const int hi = lane >> 5;
  const int b = bh >> 3, h = bh & 7;

  const __hip_bfloat16* Kh = Kc + bh * (Sc * 64);   // frag-major
  const __hip_bfloat16* Vh = Vt + bh * (Sc * 64);   // frag-major

  // Q frags straight from f32 input (scale folded into exp2 arg)
  bf16x8 qf[2][4];
#pragma unroll
  for (int g = 0; g < 2; ++g) {
    const float* qrow = Qf + ((b * Lc + q0 + g * 32 + qi) * Hc + h) * 64 + hi * 8;
#pragma unroll
    for (int es = 0; es < 4; ++es) {
      float4 a = *reinterpret_cast<const float4*>(qrow + es * 16);
      float4 c = *reinterpret_cast<const float4*>(qrow + es * 16 + 4);
      qf[g][es] = pack4(pkbf(a.x, a.y), pkbf(a.z, a.w), pkbf(c.x, c.y), pkbf(c.z, c.w));
    }
  }

  f32x16 zero;
#pragma unroll
  for (int r = 0; r < 16; ++r) zero[r] = 0.f;      // loop-invariant MFMA C-input

  f32x16 oa0 = zero, ob0 = zero, oa1 = zero, ob1 = zero;
  float m0 = -1.0e30f, l0 = 0.f, m1 = -1.0e30f, l1 = 0.f;

  bf16x8 kA0, kA1, kA2, kA3, vA0, vA1, vA2, vA3;
  bf16x8 kB0, kB1, kB2, kB3, vB0, vB1, vB2, vB3;

  auto loadKV = [&](bf16x8& k0, bf16x8& k1, bf16x8& k2, bf16x8& k3,
                    bf16x8& v0, bf16x8& v1, bf16x8& v2, bf16x8& v3, int s) {
    const __hip_bfloat16* Kp = Kh + (s >> 5) * 2048 + lane * 8;
    k0 = *reinterpret_cast<const bf16x8*>(Kp + 0 * 512);
    k1 = *reinterpret_cast<const bf16x8*>(Kp + 1 * 512);
    k2 = *reinterpret_cast<const bf16x8*>(Kp + 2 * 512);
    k3 = *reinterpret_cast<const bf16x8*>(Kp + 3 * 512);
    const __hip_bfloat16* Vp = Vh + (s >> 5) * 2048 + lane * 8;
    v0 = *reinterpret_cast<const bf16x8*>(Vp + 0 * 512);
    v1 = *reinterpret_cast<const bf16x8*>(Vp + 1 * 512);
    v2 = *reinterpret_cast<const bf16x8*>(Vp + 2 * 512);
    v3 = *reinterpret_cast<const bf16x8*>(Vp + 3 * 512);
  };

  auto compute = [&](bf16x8 k0, bf16x8 k1, bf16x8 k2, bf16x8 k3,
                     bf16x8 v0, bf16x8 v1, bf16x8 v2, bf16x8 v3) {
    f32x16 sc0, sc1;
    __builtin_amdgcn_s_setprio(1);
    sc0 = __builtin_amdgcn_mfma_f32_32x32x16_bf16(k0, qf[0][0], zero, 0, 0, 0);
    sc0 = __builtin_amdgcn_mfma_f32_32x32x16_bf16(k1, qf[0][1], sc0, 0, 0, 0);
    sc0 = __builtin_amdgcn_mfma_f32_32x32x16_bf16(k2, qf[0][2], sc0, 0, 0, 0);
    sc0 = __builtin_amdgcn_mfma_f32_32x32x16_bf16(k3, qf[0][3], sc0, 0, 0, 0);
    sc1 = __builtin_amdgcn_mfma_f32_32x32x16_bf16(k0, qf[1][0], zero, 0, 0, 0);
    sc1 = __builtin_amdgcn_mfma_f32_32x32x16_bf16(k1, qf[1][1], sc1, 0, 0, 0);
    sc1 = __builtin_amdgcn_mfma_f32_32x32x16_bf16(k2, qf[1][2], sc1, 0, 0, 0);
    sc1 = __builtin_amdgcn_mfma_f32_32x32x16_bf16(k3, qf[1][3], sc1, 0, 0, 0);
    __builtin_amdgcn_s_setprio(0);

    bf16x8 pb0, pb1;
    sm_group(sc0, m0, l0, oa0, ob0, hi, pb0, pb1);
    __builtin_amdgcn_s_setprio(1);
    oa0 = __builtin_amdgcn_mfma_f32_32x32x16_bf16(v0, pb0, oa0, 0, 0, 0);
    oa0 = __builtin_amdgcn_mfma_f32_32x32x16_bf16(v1, pb1, oa0, 0, 0, 0);
    ob0 = __builtin_amdgcn_mfma_f32_32x32x16_bf16(v2, pb0, ob0, 0, 0, 0);
    ob0 = __builtin_amdgcn_mfma_f32_32x32x16_bf16(v3, pb1, ob0, 0, 0, 0);
    __builtin_amdgcn_s_setprio(0);

    sm_group(sc1, m1, l1, oa1, ob1, hi, pb0, pb1);
    __builtin_amdgcn_s_setprio(1);
    oa1 = __builtin_amdgcn_mfma_f32_32x32x16_bf16(v0, pb0, oa1, 0, 0, 0);
    oa1 = __builtin_amdgcn_mfma_f32_32x32x16_bf16(v1, pb1, oa1, 0, 0, 0);
    ob1 = __builtin_amdgcn_mfma_f32_32x32x16_bf16(v2, pb0, ob1, 0, 0, 0);
    ob1 = __builtin_amdgcn_mfma_f32_32x32x16_bf16(v3, pb1, ob1, 0, 0, 0);
    __builtin_amdgcn_s_setprio(0);
  };

  // 1-deep pipeline: wave w covers s = w*32 + 128k, k=0..15, as 8 pairs (s, s+128).
  loadKV(kA0, kA1, kA2, kA3, vA0, vA1, vA2, vA3, w * 32);
  for (int s = w * 32; s < Sc; s += 256) {
    loadKV(kB0, kB1, kB2, kB3, vB0, vB1, vB2, vB3, s + 128);   // always in range
    compute(kA0, kA1, kA2, kA3, vA0, vA1, vA2, vA3);
    if (s + 256 < Sc)
      loadKV(kA0, kA1, kA2, kA3, vA0, vA1, vA2, vA3, s + 256);
    compute(kB0, kB1, kB2, kB3, vB0, vB1, vB2, vB3);
  }

  // combine per-half l partials -> full row sums
  l0 = cross_half_sum(l0, hi);
  l1 = cross_half_sum(l1, hi);

  // ---- cross-wave combine (4 S-split partials), per q-group through shared obuf ----
  if (hi == 0) {
    mlb[0][w][0][qi] = m0; mlb[0][w][1][qi] = l0;
    mlb[1][w][0][qi] = m1; mlb[1][w][1][qi] = l1;
  }
  __syncthreads();
  float myf[2], inv[2];
#pragma unroll
  for (int g = 0; g < 2; ++g) {
    float mm = fmaxf(fmaxf(mlb[g][0][0][qi], mlb[g][1][0][qi]),
                     fmaxf(mlb[g][2][0][qi], mlb[g][3][0][qi]));
    float Lt = 0.f;
#pragma unroll
    for (int sw = 0; sw < 4; ++sw)
      Lt += EXP2((mlb[g][sw][0][qi] - mm) * SCL2) * mlb[g][sw][1][qi];
    float mreg = g ? m1 : m0;
    myf[g] = EXP2((mreg - mm) * SCL2);
    inv[g] = 1.0f / Lt;
  }
  const int d0 = w >> 1, rr = (w & 1) * 8;
#pragma unroll
  for (int g = 0; g < 2; ++g) {
    if (g) __syncthreads();
    const f32x16& A = g ? oa1 : oa0;
    const f32x16& Bv = g ? ob1 : ob0;
#pragma unroll
    for (int r = 0; r < 16; ++r) {
      obuf[w][0][r][lane] = A[r] * myf[g];
      obuf[w][1][r][lane] = Bv[r] * myf[g];
    }
    __syncthreads();
    float* orow = Out + ((b * Lc + q0 + g * 32 + qi) * Hc + h) * Dc;
#pragma unroll
    for (int t = 0; t < 2; ++t) {
      f32x4 acc;
#pragma unroll
      for (int j = 0; j < 4; ++j) {
        const int r = rr + 4 * t + j;
        acc[j] = (obuf[0][d0][r][lane] + obuf[1][d0][r][lane] +
                  obuf[2][d0][r][lane] + obuf[3][d0][r][lane]) * inv[g];
      }
      const int dbase = d0 * 32 + ((rr + 4 * t) >> 2) * 8 + hi * 4;
      *reinterpret_cast<f32x4*>(orow + dbase) = acc;
    }
  }
}

extern "C" void kernel_launch(void* const* d_in, const int* in_sizes, int n_in,
                              void* d_out, int out_size, void* d_ws, size_t ws_size,
                              hipStream_t stream) {
  const float* Q = (const float*)d_in[0];
  const float* K = (const float*)d_in[1];
  const float* V = (const float*)d_in[2];
  float* out = (float*)d_out;

  __hip_bfloat16* Kc = (__hip_bfloat16*)d_ws;       // 4 MiB
  __hip_bfloat16* Vt = Kc + ELEMS;                   // 4 MiB

  // fused prepass: blocks [0,1024) K relayout, [1024,1152) V transpose
  prep_kv_kernel<<<dim3(1152), 256, 0, stream>>>(K, V, Kc, Vt);
  // attention: 512 blocks = 8 XCD x 2 heads x 32 q-tiles (64 rows each)
  attn_kernel<<<dim3(512), 256, 0, stream>>>(Q, Kc, Vt, out);
}